// Round 4
// baseline (243.988 us; speedup 1.0000x reference)
//
#include <hip/hip_runtime.h>
#include <stdint.h>

// KeyValueMemoryNetwork: B=16, S=2048, C=16, D=256, V=100000
// R4: gather rows global->LDS via global_load_lds (no VGPR destinations ->
// compiler cannot serialize the gather; 16 KB in flight per wave).
// One wave per token; 2 tokens per 128-thread block; 32 KB LDS/block.

#define KV_C 16
#define KV_D 256
#define KV_TOKENS (16 * 2048)
#define TOK_PER_BLK 2

typedef __attribute__((address_space(3))) void       lds_void;
typedef const __attribute__((address_space(1))) void gbl_void;

__global__ __launch_bounds__(128) void kv_mem_kernel(
    const int* __restrict__ seq,      // [TOKENS, C] int32
    const float* __restrict__ hidden, // [TOKENS, D]
    const float* __restrict__ table,  // [V, D]
    float* __restrict__ out)          // [TOKENS, D]
{
    // 2 tokens * 16 rows * 256 floats = 8192 floats = 32 KB
    __shared__ float smem[TOK_PER_BLK * KV_C * KV_D];

    const int wave = threadIdx.x >> 6;
    const int lane = threadIdx.x & 63;
    const int token = blockIdx.x * TOK_PER_BLK + wave;

    float* lbase = smem + wave * (KV_C * KV_D);

    // lanes 0..15 hold the 16 indices; wave-uniform broadcast via shuffle
    const int* sp = seq + (size_t)token * KV_C;
    int myidx = (lane < KV_C) ? sp[lane] : 0;
    const unsigned long long nz = __ballot(myidx != 0);

    int idxs[KV_C];
    #pragma unroll
    for (int c = 0; c < KV_C; ++c) idxs[c] = __shfl(myidx, c);

    // hidden chunk for this lane (in flight alongside the gathers)
    const float4 h = *(const float4*)(hidden + (size_t)token * KV_D + lane * 4);

    // Stage all 16 rows into LDS: no VGPR destinations, nothing to spill,
    // all 16 KB outstanding at once. Lane l's 16 B of row c lands at
    // lbase + c*1024 + l*16 (wave-uniform base + lane*size — exact match).
    #pragma unroll
    for (int c = 0; c < KV_C; ++c) {
        const float* gp = table + (size_t)idxs[c] * KV_D + lane * 4;
        __builtin_amdgcn_global_load_lds((gbl_void*)gp,
                                         (lds_void*)(lbase + c * KV_D),
                                         16, 0, 0);
    }

    // Wave-internal wait: this wave only reads LDS it wrote itself.
    asm volatile("s_waitcnt vmcnt(0)" ::: "memory");

    // Phase 1: per-lane partial dots from LDS (rows die immediately -> no
    // register pressure). Padded slots (idx==0) -> u = 0 exactly.
    float u[KV_C];
    #pragma unroll
    for (int c = 0; c < KV_C; ++c) {
        const float4 ev = *(const float4*)(lbase + c * KV_D + lane * 4);
        const float msk = ((nz >> c) & 1ULL) ? 1.0f : 0.0f;
        u[c] = msk * (h.x * ev.x + h.y * ev.y + h.z * ev.z + h.w * ev.w);
    }

    // butterfly reduce 16 scores across the 64-lane wave
    #pragma unroll
    for (int s = 32; s >= 1; s >>= 1) {
        #pragma unroll
        for (int c = 0; c < KV_C; ++c) {
            u[c] += __shfl_xor(u[c], s);
        }
    }

    // softmax over C (wave-uniform, redundant per lane)
    float m = u[0];
    #pragma unroll
    for (int c = 1; c < KV_C; ++c) m = fmaxf(m, u[c]);
    float sum = 0.f;
    #pragma unroll
    for (int c = 0; c < KV_C; ++c) {
        u[c] = __expf(u[c] - m);
        sum += u[c];
    }
    const float inv = 1.0f / sum;

    // Phase 2: weighted combine, re-reading rows from LDS.
    float4 o = make_float4(0.f, 0.f, 0.f, 0.f);
    #pragma unroll
    for (int c = 0; c < KV_C; ++c) {
        const float4 ev = *(const float4*)(lbase + c * KV_D + lane * 4);
        const float msk = ((nz >> c) & 1ULL) ? 1.0f : 0.0f;
        const float w = u[c] * inv * msk;
        o.x += w * ev.x;
        o.y += w * ev.y;
        o.z += w * ev.z;
        o.w += w * ev.w;
    }

    *(float4*)(out + (size_t)token * KV_D + lane * 4) = o;
}

extern "C" void kernel_launch(void* const* d_in, const int* in_sizes, int n_in,
                              void* d_out, int out_size, void* d_ws, size_t ws_size,
                              hipStream_t stream) {
    const int*   seq    = (const int*)d_in[0];
    const float* hidden = (const float*)d_in[1];
    const float* table  = (const float*)d_in[2];
    float*       out    = (float*)d_out;

    dim3 grid(KV_TOKENS / TOK_PER_BLK);   // 16384 blocks, 2 tokens each
    dim3 block(128);
    kv_mem_kernel<<<grid, block, 0, stream>>>(seq, hidden, table, out);
}

// Round 5
// 228.090 us; speedup vs baseline: 1.0697x; 1.0697x over previous
//
#include <hip/hip_runtime.h>

// KeyValueMemoryNetwork: B=16, S=2048, C=16, D=256, V=100000
// R5: pure-register gather + ONLINE SOFTMAX over 2 chunks of 8 rows.
// Each row is loaded once and consumed (dot + combine) while live ->
// only 8 rows resident (32 VGPRs), nothing to rematerialize, 8 KB/wave
// in flight, no LDS (zero bank conflicts), high occupancy.

#define KV_C 16
#define KV_D 256
#define KV_CHUNK 8
#define KV_TOKENS (16 * 2048)

__global__ __launch_bounds__(256, 4) void kv_mem_kernel(
    const int* __restrict__ seq,      // [TOKENS, C] int32
    const float* __restrict__ hidden, // [TOKENS, D]
    const float* __restrict__ table,  // [V, D]
    float* __restrict__ out)          // [TOKENS, D]
{
    const int wave = threadIdx.x >> 6;
    const int lane = threadIdx.x & 63;
    const int token = blockIdx.x * 4 + wave;

    // hidden chunk for this lane
    const float4 h = *(const float4*)(hidden + (size_t)token * KV_D + lane * 4);

    // lanes 0..15 hold the 16 indices; broadcast via shuffle
    const int* sp = seq + (size_t)token * KV_C;
    int myidx = (lane < KV_C) ? sp[lane] : 0;
    const unsigned long long nz = __ballot(myidx != 0);

    // online-softmax state (wave-uniform after each chunk's reduce)
    float m_run = 0.0f;   // acts as -inf: l_run==0 and o==0 make it safe
    float l_run = 0.0f;
    float4 o = make_float4(0.f, 0.f, 0.f, 0.f);

    #pragma unroll
    for (int ch = 0; ch < KV_C / KV_CHUNK; ++ch) {
        const int cbase = ch * KV_CHUNK;

        // Phase A: 8 unconditional gathers, back-to-back (row 0 is valid
        // memory; padding handled by mask below).
        float4 e[KV_CHUNK];
        #pragma unroll
        for (int j = 0; j < KV_CHUNK; ++j) {
            const int idx = __shfl(myidx, cbase + j);   // wave-uniform
            e[j] = *(const float4*)(table + (size_t)idx * KV_D + lane * 4);
        }

        // Phase B: partial dots (masked -> padded slots give u == 0 exactly,
        // matching the reference, which softmaxes over zero rows too).
        float u[KV_CHUNK];
        #pragma unroll
        for (int j = 0; j < KV_CHUNK; ++j) {
            const float msk = ((nz >> (cbase + j)) & 1ULL) ? 1.0f : 0.0f;
            u[j] = msk * (h.x * e[j].x + h.y * e[j].y +
                          h.z * e[j].z + h.w * e[j].w);
        }

        // butterfly reduce the 8 scores across the 64-lane wave
        #pragma unroll
        for (int s = 32; s >= 1; s >>= 1) {
            #pragma unroll
            for (int j = 0; j < KV_CHUNK; ++j) {
                u[j] += __shfl_xor(u[j], s);
            }
        }

        // Phase C: online-softmax update + combine while rows are live.
        float m_new = m_run;
        #pragma unroll
        for (int j = 0; j < KV_CHUNK; ++j) m_new = fmaxf(m_new, u[j]);
        const float scale = __expf(m_run - m_new);
        l_run *= scale;
        o.x *= scale; o.y *= scale; o.z *= scale; o.w *= scale;
        #pragma unroll
        for (int j = 0; j < KV_CHUNK; ++j) {
            const float w = __expf(u[j] - m_new);
            l_run += w;                                   // Z includes padded slots
            const float msk = ((nz >> (cbase + j)) & 1ULL) ? 1.0f : 0.0f;
            const float wm = w * msk;                     // zero vector into o
            o.x += wm * e[j].x;
            o.y += wm * e[j].y;
            o.z += wm * e[j].z;
            o.w += wm * e[j].w;
        }
        m_run = m_new;
    }

    const float inv = 1.0f / l_run;
    o.x *= inv; o.y *= inv; o.z *= inv; o.w *= inv;

    *(float4*)(out + (size_t)token * KV_D + lane * 4) = o;
}

extern "C" void kernel_launch(void* const* d_in, const int* in_sizes, int n_in,
                              void* d_out, int out_size, void* d_ws, size_t ws_size,
                              hipStream_t stream) {
    const int*   seq    = (const int*)d_in[0];
    const float* hidden = (const float*)d_in[1];
    const float* table  = (const float*)d_in[2];
    float*       out    = (float*)d_out;

    dim3 grid(KV_TOKENS / 4);   // 8192 blocks, 4 waves (tokens) per block
    dim3 block(256);
    kv_mem_kernel<<<grid, block, 0, stream>>>(seq, hidden, table, out);
}